// Round 1
// baseline (2760.321 us; speedup 1.0000x reference)
//
#include <hip/hip_runtime.h>

#define LEAKY(v) ((v) >= 0.0f ? (v) : 0.01f * (v))

constexpr int D = 256;  // in = hid = out = 256

// ---------------- big GEMM: C[M,D] = f(A[M,D]) @ W[D..,D] (+epilogue) --------
// IN_BIAS_LEAKY: A' = leaky(A + in_bias[k]) applied on load
// ADD_ROW:       C += R[batch[row]][col]
// ADD_BIAS:      C += bias[col]
// OUT_LEAKY:     C = leaky(C)
template <bool IN_BIAS_LEAKY, bool ADD_ROW, bool ADD_BIAS, bool OUT_LEAKY>
__global__ __launch_bounds__(256) void gemm_fused(
    const float* __restrict__ A, const float* __restrict__ W,
    const float* __restrict__ in_bias, const float* __restrict__ R,
    const int* __restrict__ batch, const float* __restrict__ bias,
    float* __restrict__ C, int M) {
  __shared__ float As[16][64 + 4];
  __shared__ float Bs[16][64 + 4];
  const int tid = threadIdx.x;
  const int tx = tid & 15;   // n-dir
  const int ty = tid >> 4;   // m-dir
  const int rowBase = blockIdx.x * 64;
  const int colBase = blockIdx.y * 64;

  float acc[4][4] = {};

  const int lr = tid >> 2;        // 0..63  A-tile row
  const int lk = (tid & 3) * 4;   // 0,4,8,12 k-offset
  const int wr = tid >> 4;        // 0..15  W-tile k row
  const int wc = (tid & 15) * 4;  // col offset

  for (int k0 = 0; k0 < D; k0 += 16) {
    {
      int row = rowBase + lr;
      float4 v = make_float4(0.f, 0.f, 0.f, 0.f);
      if (row < M) v = *(const float4*)(A + (size_t)row * D + k0 + lk);
      if (IN_BIAS_LEAKY) {
        v.x += in_bias[k0 + lk + 0];
        v.y += in_bias[k0 + lk + 1];
        v.z += in_bias[k0 + lk + 2];
        v.w += in_bias[k0 + lk + 3];
        v.x = LEAKY(v.x); v.y = LEAKY(v.y);
        v.z = LEAKY(v.z); v.w = LEAKY(v.w);
      }
      As[lk + 0][lr] = v.x; As[lk + 1][lr] = v.y;
      As[lk + 2][lr] = v.z; As[lk + 3][lr] = v.w;
    }
    {
      float4 v = *(const float4*)(W + (size_t)(k0 + wr) * D + colBase + wc);
      Bs[wr][wc + 0] = v.x; Bs[wr][wc + 1] = v.y;
      Bs[wr][wc + 2] = v.z; Bs[wr][wc + 3] = v.w;
    }
    __syncthreads();
#pragma unroll
    for (int kk = 0; kk < 16; kk++) {
      float a[4], b[4];
#pragma unroll
      for (int i = 0; i < 4; i++) a[i] = As[kk][ty * 4 + i];
#pragma unroll
      for (int j = 0; j < 4; j++) b[j] = Bs[kk][tx * 4 + j];
#pragma unroll
      for (int i = 0; i < 4; i++)
#pragma unroll
        for (int j = 0; j < 4; j++) acc[i][j] += a[i] * b[j];
    }
    __syncthreads();
  }

#pragma unroll
  for (int i = 0; i < 4; i++) {
    int row = rowBase + ty * 4 + i;
    if (row < M) {
      int rb = ADD_ROW ? batch[row] : 0;
#pragma unroll
      for (int j = 0; j < 4; j++) {
        int col = colBase + tx * 4 + j;
        float c = acc[i][j];
        if (ADD_ROW) c += R[(size_t)rb * D + col];
        if (ADD_BIAS) c += bias[col];
        if (OUT_LEAKY) c = LEAKY(c);
        C[(size_t)row * D + col] = c;
      }
    }
  }
}

// ------------- edge scatter: agg[dst] += w * H[src], one wave per edge ------
__global__ __launch_bounds__(256) void scatter_edges(
    const float* __restrict__ H, const float* __restrict__ vals,
    const int* __restrict__ src, const int* __restrict__ dst,
    float* __restrict__ agg, int E) {
  int e = blockIdx.x * 4 + (threadIdx.x >> 6);
  if (e >= E) return;
  int lane = threadIdx.x & 63;
  int s = src[e];
  int d = dst[e];
  float w = vals[e];
  float4 v = ((const float4*)(H + (size_t)s * D))[lane];
  float* ap = agg + (size_t)d * D + lane * 4;
  atomicAdd(ap + 0, w * v.x);
  atomicAdd(ap + 1, w * v.y);
  atomicAdd(ap + 2, w * v.z);
  atomicAdd(ap + 3, w * v.w);
}

// ------ tiny root GEMM: R[b,:] = f(X[root_idx[b],:]) @ W[256x256] -----------
__global__ __launch_bounds__(256) void root_gemm(
    const float* __restrict__ X, const int* __restrict__ root_idx,
    const float* __restrict__ W, const float* __restrict__ in_bias,
    int in_leaky, float* __restrict__ R) {
  __shared__ float a[D];
  int b = blockIdx.x;
  int j = threadIdx.x;
  int r = root_idx[b];
  float v = X[(size_t)r * D + j];
  if (in_bias) v += in_bias[j];
  if (in_leaky) v = LEAKY(v);
  a[j] = v;
  __syncthreads();
  float acc = 0.f;
#pragma unroll 8
  for (int k = 0; k < D; k++) acc += a[k] * W[(size_t)k * D + j];
  R[(size_t)b * D + j] = acc;
}

extern "C" void kernel_launch(void* const* d_in, const int* in_sizes, int n_in,
                              void* d_out, int out_size, void* d_ws,
                              size_t ws_size, hipStream_t stream) {
  const float* features = (const float*)d_in[0];  // [N,256]
  const float* values   = (const float*)d_in[1];  // [E]
  const float* W1 = (const float*)d_in[2];        // [256,256]
  const float* b1 = (const float*)d_in[3];        // [256]
  const float* W2 = (const float*)d_in[4];        // [512,256]
  const float* b2 = (const float*)d_in[5];        // [256]
  const float* Wl = (const float*)d_in[6];        // [512,256]
  const float* bl = (const float*)d_in[7];        // [256]
  const int* adjs = (const int*)d_in[8];          // [2,E]
  const int* batch = (const int*)d_in[9];         // [N]
  const int* root_idx = (const int*)d_in[10];     // [B]

  const int N = in_sizes[0] / D;
  const int E = in_sizes[1];
  const int B = in_sizes[10];
  const int* srcI = adjs;
  const int* dstI = adjs + E;

  float* buf0 = (float*)d_ws;             // h0, then h2
  float* buf1 = buf0 + (size_t)N * D;     // agg1, then agg2
  float* R1 = buf1 + (size_t)N * D;       // [B,256]
  float* R2 = R1 + (size_t)B * D;         // [B,256]

  dim3 gblk(256);
  dim3 ggrid((N + 63) / 64, D / 64);

  // 1) h0 = features @ W1
  gemm_fused<false, false, false, false><<<ggrid, gblk, 0, stream>>>(
      features, W1, nullptr, nullptr, nullptr, nullptr, buf0, N);

  // 2) agg1 = segsum(w * h0[src] -> dst)
  hipMemsetAsync(buf1, 0, (size_t)N * D * sizeof(float), stream);
  scatter_edges<<<(E + 3) / 4, 256, 0, stream>>>(buf0, values, srcI, dstI,
                                                 buf1, E);

  // 3) R1 = leaky(features[root]) @ W2[256:512]; R2 = (agg1[root]+b1) @ Wl[256:512]
  root_gemm<<<B, 256, 0, stream>>>(features, root_idx, W2 + (size_t)D * D,
                                   nullptr, 1, R1);
  root_gemm<<<B, 256, 0, stream>>>(buf1, root_idx, Wl + (size_t)D * D, b1, 0,
                                   R2);

  // 4) h2 = leaky(agg1 + b1) @ W2[0:256] + R1[batch]
  gemm_fused<true, true, false, false><<<ggrid, gblk, 0, stream>>>(
      buf1, W2, b1, R1, batch, nullptr, buf0, N);

  // 5) agg2 = segsum(w * h2[src] -> dst)
  hipMemsetAsync(buf1, 0, (size_t)N * D * sizeof(float), stream);
  scatter_edges<<<(E + 3) / 4, 256, 0, stream>>>(buf0, values, srcI, dstI,
                                                 buf1, E);

  // 6) out = leaky( leaky(agg2 + b2) @ Wl[0:256] + R2[batch] + bl )
  gemm_fused<true, true, true, true><<<ggrid, gblk, 0, stream>>>(
      buf1, Wl, b2, R2, batch, bl, (float*)d_out, N);
}

// Round 2
// 893.831 us; speedup vs baseline: 3.0882x; 3.0882x over previous
//
#include <hip/hip_runtime.h>

#define LEAKY(v) ((v) >= 0.0f ? (v) : 0.01f * (v))

constexpr int D = 256;  // in = hid = out = 256

// ---------------- big GEMM: C[M,D] = f(A[M,D]) @ W[D..,D] (+epilogue) --------
template <bool IN_BIAS_LEAKY, bool ADD_ROW, bool ADD_BIAS, bool OUT_LEAKY>
__global__ __launch_bounds__(256) void gemm_fused(
    const float* __restrict__ A, const float* __restrict__ W,
    const float* __restrict__ in_bias, const float* __restrict__ R,
    const int* __restrict__ batch, const float* __restrict__ bias,
    float* __restrict__ C, int M) {
  __shared__ float As[16][64 + 4];
  __shared__ float Bs[16][64 + 4];
  const int tid = threadIdx.x;
  const int tx = tid & 15;   // n-dir
  const int ty = tid >> 4;   // m-dir
  const int rowBase = blockIdx.x * 64;
  const int colBase = blockIdx.y * 64;

  float acc[4][4] = {};

  const int lr = tid >> 2;        // 0..63  A-tile row
  const int lk = (tid & 3) * 4;   // 0,4,8,12 k-offset
  const int wr = tid >> 4;        // 0..15  W-tile k row
  const int wc = (tid & 15) * 4;  // col offset

  for (int k0 = 0; k0 < D; k0 += 16) {
    {
      int row = rowBase + lr;
      float4 v = make_float4(0.f, 0.f, 0.f, 0.f);
      if (row < M) v = *(const float4*)(A + (size_t)row * D + k0 + lk);
      if (IN_BIAS_LEAKY) {
        v.x += in_bias[k0 + lk + 0];
        v.y += in_bias[k0 + lk + 1];
        v.z += in_bias[k0 + lk + 2];
        v.w += in_bias[k0 + lk + 3];
        v.x = LEAKY(v.x); v.y = LEAKY(v.y);
        v.z = LEAKY(v.z); v.w = LEAKY(v.w);
      }
      As[lk + 0][lr] = v.x; As[lk + 1][lr] = v.y;
      As[lk + 2][lr] = v.z; As[lk + 3][lr] = v.w;
    }
    {
      float4 v = *(const float4*)(W + (size_t)(k0 + wr) * D + colBase + wc);
      Bs[wr][wc + 0] = v.x; Bs[wr][wc + 1] = v.y;
      Bs[wr][wc + 2] = v.z; Bs[wr][wc + 3] = v.w;
    }
    __syncthreads();
#pragma unroll
    for (int kk = 0; kk < 16; kk++) {
      float a[4], b[4];
#pragma unroll
      for (int i = 0; i < 4; i++) a[i] = As[kk][ty * 4 + i];
#pragma unroll
      for (int j = 0; j < 4; j++) b[j] = Bs[kk][tx * 4 + j];
#pragma unroll
      for (int i = 0; i < 4; i++)
#pragma unroll
        for (int j = 0; j < 4; j++) acc[i][j] += a[i] * b[j];
    }
    __syncthreads();
  }

#pragma unroll
  for (int i = 0; i < 4; i++) {
    int row = rowBase + ty * 4 + i;
    if (row < M) {
      int rb = ADD_ROW ? batch[row] : 0;
#pragma unroll
      for (int j = 0; j < 4; j++) {
        int col = colBase + tx * 4 + j;
        float c = acc[i][j];
        if (ADD_ROW) c += R[(size_t)rb * D + col];
        if (ADD_BIAS) c += bias[col];
        if (OUT_LEAKY) c = LEAKY(c);
        C[(size_t)row * D + col] = c;
      }
    }
  }
}

// ---------------- CSR build --------------------------------------------------
__global__ void count_dst(const int* __restrict__ dst, int* __restrict__ offs,
                          int E) {
  int e = blockIdx.x * 256 + threadIdx.x;
  if (e < E) atomicAdd(&offs[dst[e]], 1);
}

// per-block exclusive scan of offs (in-place) + block sums
__global__ void scan_blocks(int* __restrict__ offs, int* __restrict__ bsums,
                            int n) {
  __shared__ int tmp[256];
  int i = blockIdx.x * 256 + threadIdx.x;
  int v = (i < n) ? offs[i] : 0;
  tmp[threadIdx.x] = v;
  __syncthreads();
  for (int off = 1; off < 256; off <<= 1) {
    int t = (threadIdx.x >= off) ? tmp[threadIdx.x - off] : 0;
    __syncthreads();
    tmp[threadIdx.x] += t;
    __syncthreads();
  }
  if (i < n) offs[i] = tmp[threadIdx.x] - v;  // exclusive within block
  if (threadIdx.x == 255) bsums[blockIdx.x] = tmp[255];
}

// single-block exclusive scan of block sums (nb <= 1024)
__global__ void scan_sums(int* __restrict__ bs, int nb) {
  __shared__ int tmp[1024];
  int v = (threadIdx.x < nb) ? bs[threadIdx.x] : 0;
  tmp[threadIdx.x] = v;
  __syncthreads();
  for (int off = 1; off < 1024; off <<= 1) {
    int t = (threadIdx.x >= off) ? tmp[threadIdx.x - off] : 0;
    __syncthreads();
    tmp[threadIdx.x] += t;
    __syncthreads();
  }
  if (threadIdx.x < nb) bs[threadIdx.x] = tmp[threadIdx.x] - v;
}

__global__ void add_offsets(int* __restrict__ offs, const int* __restrict__ bs,
                            int n, int* __restrict__ cursor) {
  int i = blockIdx.x * 256 + threadIdx.x;
  if (i < n) {
    int o = offs[i] + bs[blockIdx.x];
    offs[i] = o;
    cursor[i] = o;
  }
}

__global__ void fill_buckets(const int* __restrict__ src,
                             const int* __restrict__ dst,
                             const float* __restrict__ vals,
                             int* __restrict__ cursor, int* __restrict__ esrc,
                             float* __restrict__ ew, int E) {
  int e = blockIdx.x * 256 + threadIdx.x;
  if (e < E) {
    int p = atomicAdd(&cursor[dst[e]], 1);
    esrc[p] = src[e];
    ew[p] = vals[e];
  }
}

// --------- gather aggregation: agg[n] = sum_{e in bucket(n)} w_e * H[src_e] --
__global__ __launch_bounds__(256) void aggregate_csr(
    const float* __restrict__ H, const int* __restrict__ offs,
    const int* __restrict__ esrc, const float* __restrict__ ew,
    float* __restrict__ agg, int N, int E) {
  int node = blockIdx.x * 4 + (threadIdx.x >> 6);
  if (node >= N) return;
  int lane = threadIdx.x & 63;
  int beg = offs[node];
  int end = (node == N - 1) ? E : offs[node + 1];
  float4 acc = make_float4(0.f, 0.f, 0.f, 0.f);
  for (int i = beg; i < end; i++) {
    int s = esrc[i];
    float w = ew[i];
    float4 v = ((const float4*)(H + (size_t)s * D))[lane];
    acc.x += w * v.x;
    acc.y += w * v.y;
    acc.z += w * v.z;
    acc.w += w * v.w;
  }
  ((float4*)(agg + (size_t)node * D))[lane] = acc;
}

// ------ tiny root GEMM: R[b,:] = f(X[root_idx[b],:]) @ W[256x256] -----------
__global__ void root_gemm(const float* __restrict__ X,
                          const int* __restrict__ root_idx,
                          const float* __restrict__ W,
                          const float* __restrict__ in_bias, int in_leaky,
                          float* __restrict__ R) {
  __shared__ float a[D];
  int b = blockIdx.x;
  int j = threadIdx.x;
  int r = root_idx[b];
  float v = X[(size_t)r * D + j];
  if (in_bias) v += in_bias[j];
  if (in_leaky) v = LEAKY(v);
  a[j] = v;
  __syncthreads();
  float acc = 0.f;
#pragma unroll 8
  for (int k = 0; k < D; k++) acc += a[k] * W[(size_t)k * D + j];
  R[(size_t)b * D + j] = acc;
}

extern "C" void kernel_launch(void* const* d_in, const int* in_sizes, int n_in,
                              void* d_out, int out_size, void* d_ws,
                              size_t ws_size, hipStream_t stream) {
  const float* features = (const float*)d_in[0];  // [N,256]
  const float* values   = (const float*)d_in[1];  // [E]
  const float* W1 = (const float*)d_in[2];        // [256,256]
  const float* b1 = (const float*)d_in[3];        // [256]
  const float* W2 = (const float*)d_in[4];        // [512,256]
  const float* b2 = (const float*)d_in[5];        // [256]
  const float* Wl = (const float*)d_in[6];        // [512,256]
  const float* bl = (const float*)d_in[7];        // [256]
  const int* adjs = (const int*)d_in[8];          // [2,E]
  const int* batch = (const int*)d_in[9];         // [N]
  const int* root_idx = (const int*)d_in[10];     // [B]

  const int N = in_sizes[0] / D;
  const int E = in_sizes[1];
  const int B = in_sizes[10];
  const int* srcI = adjs;
  const int* dstI = adjs + E;

  // workspace layout
  float* buf0 = (float*)d_ws;             // h0, then h2
  float* buf1 = buf0 + (size_t)N * D;     // agg1, then agg2
  float* R1 = buf1 + (size_t)N * D;       // [B,256]
  float* R2 = R1 + (size_t)B * D;         // [B,256]
  float* ew = R2 + (size_t)B * D;         // [E]
  int* offs = (int*)(ew + E);             // [N]
  int* cursor = offs + N;                 // [N]
  int* esrc = cursor + N;                 // [E]
  int* bsums = esrc + E;                  // [<=1024]

  const int nb = (N + 255) / 256;  // <= 1024 assumed (N=100k -> 391)

  // ---- build dst-CSR once (reused by both aggregations) ----
  hipMemsetAsync(offs, 0, (size_t)N * sizeof(int), stream);
  count_dst<<<(E + 255) / 256, 256, 0, stream>>>(dstI, offs, E);
  scan_blocks<<<nb, 256, 0, stream>>>(offs, bsums, N);
  scan_sums<<<1, 1024, 0, stream>>>(bsums, nb);
  add_offsets<<<nb, 256, 0, stream>>>(offs, bsums, N, cursor);
  fill_buckets<<<(E + 255) / 256, 256, 0, stream>>>(srcI, dstI, values, cursor,
                                                    esrc, ew, E);

  dim3 gblk(256);
  dim3 ggrid((N + 63) / 64, D / 64);
  const int aggGrid = (N + 3) / 4;

  // 1) h0 = features @ W1
  gemm_fused<false, false, false, false><<<ggrid, gblk, 0, stream>>>(
      features, W1, nullptr, nullptr, nullptr, nullptr, buf0, N);

  // 2) agg1 = segsum(w * h0[src] -> dst)   (gather CSR, no atomics)
  aggregate_csr<<<aggGrid, 256, 0, stream>>>(buf0, offs, esrc, ew, buf1, N, E);

  // 3) R1 = leaky(features[root]) @ W2[256:512]; R2 = (agg1[root]+b1) @ Wl[256:512]
  root_gemm<<<B, 256, 0, stream>>>(features, root_idx, W2 + (size_t)D * D,
                                   nullptr, 1, R1);
  root_gemm<<<B, 256, 0, stream>>>(buf1, root_idx, Wl + (size_t)D * D, b1, 0,
                                   R2);

  // 4) h2 = leaky(agg1 + b1) @ W2[0:256] + R1[batch]
  gemm_fused<true, true, false, false><<<ggrid, gblk, 0, stream>>>(
      buf1, W2, b1, R1, batch, nullptr, buf0, N);

  // 5) agg2 = segsum(w * h2[src] -> dst)
  aggregate_csr<<<aggGrid, 256, 0, stream>>>(buf0, offs, esrc, ew, buf1, N, E);

  // 6) out = leaky( leaky(agg2 + b2) @ Wl[0:256] + R2[batch] + bl )
  gemm_fused<true, true, true, true><<<ggrid, gblk, 0, stream>>>(
      buf1, Wl, b2, R2, batch, bl, (float*)d_out, N);
}

// Round 3
// 504.048 us; speedup vs baseline: 5.4763x; 1.7733x over previous
//
#include <hip/hip_runtime.h>

typedef short short8 __attribute__((ext_vector_type(8)));
typedef float floatx4 __attribute__((ext_vector_type(4)));

#define LEAKY(v) ((v) >= 0.0f ? (v) : 0.01f * (v))

constexpr int D = 256;  // in = hid = out = 256

__device__ __forceinline__ short f2bf(float x) {
  unsigned u = __float_as_uint(x);
  u += 0x7fffu + ((u >> 16) & 1u);  // RNE (finite inputs)
  return (short)(u >> 16);
}
__device__ __forceinline__ float bf2f(short s) {
  return __uint_as_float(((unsigned)(unsigned short)s) << 16);
}

// ---- W transpose+convert: Wt[n][k] = bf16(Wsrc[k][n]), 3 matrices ----------
__global__ void transpose_w(const float* __restrict__ W1,
                            const float* __restrict__ W2,
                            const float* __restrict__ Wl,
                            short* __restrict__ Wt) {
  __shared__ float t[32][33];
  const float* src = (blockIdx.z == 0) ? W1 : (blockIdx.z == 1) ? W2 : Wl;
  short* dst = Wt + (size_t)blockIdx.z * D * D;
  int tx = threadIdx.x, ty = threadIdx.y;
  t[ty][tx] = src[(size_t)(blockIdx.y * 32 + ty) * D + blockIdx.x * 32 + tx];
  __syncthreads();
  dst[(size_t)(blockIdx.x * 32 + ty) * D + blockIdx.y * 32 + tx] =
      f2bf(t[tx][ty]);
}

// ---- MFMA GEMM: C[M,256] = A[M,256] @ Wt^T (+epilogue) ---------------------
// BM=64, BN=256 (full), BK=64. 256 threads = 4 waves; wave w covers cols
// w*64..w*64+63 via 4 n-frags; 4 m-frags of 16 rows; acc 4x4 floatx4.
template <bool A_F32, bool ADD_ROW, bool FINAL>
__global__ __launch_bounds__(256) void gemm_mfma(
    const void* __restrict__ Avoid, const short* __restrict__ Wt,
    const float* __restrict__ R, const int* __restrict__ batch,
    const float* __restrict__ bias, void* __restrict__ Cvoid, int M) {
  __shared__ __align__(16) short As[64 * 72];   // pitch 72 breaks conflicts
  __shared__ __align__(16) short Bs[256 * 72];  // [n][k]
  const int tid = threadIdx.x;
  const int l = tid & 63, w = tid >> 6, lm = l & 15, q = l >> 4;
  const int rowBase = blockIdx.x * 64;

  floatx4 acc[4][4];
#pragma unroll
  for (int i = 0; i < 4; i++)
#pragma unroll
    for (int j = 0; j < 4; j++) acc[i][j] = (floatx4){0.f, 0.f, 0.f, 0.f};

  const int arow = tid >> 2;         // 0..63
  const int akseg = (tid & 3) * 16;  // 0,16,32,48

  for (int k0 = 0; k0 < D; k0 += 64) {
    // ---- stage A tile (64 x 64 bf16) ----
    {
      int grow = rowBase + arow;
      if (A_F32) {
        short8 s0 = {0, 0, 0, 0, 0, 0, 0, 0}, s1 = {0, 0, 0, 0, 0, 0, 0, 0};
        if (grow < M) {
          const float* ap = (const float*)Avoid + (size_t)grow * D + k0 + akseg;
          float4 v0 = ((const float4*)ap)[0];
          float4 v1 = ((const float4*)ap)[1];
          float4 v2 = ((const float4*)ap)[2];
          float4 v3 = ((const float4*)ap)[3];
          s0[0] = f2bf(v0.x); s0[1] = f2bf(v0.y); s0[2] = f2bf(v0.z); s0[3] = f2bf(v0.w);
          s0[4] = f2bf(v1.x); s0[5] = f2bf(v1.y); s0[6] = f2bf(v1.z); s0[7] = f2bf(v1.w);
          s1[0] = f2bf(v2.x); s1[1] = f2bf(v2.y); s1[2] = f2bf(v2.z); s1[3] = f2bf(v2.w);
          s1[4] = f2bf(v3.x); s1[5] = f2bf(v3.y); s1[6] = f2bf(v3.z); s1[7] = f2bf(v3.w);
        }
        *(short8*)(As + arow * 72 + akseg) = s0;
        *(short8*)(As + arow * 72 + akseg + 8) = s1;
      } else {
        uint4 u0 = {0, 0, 0, 0}, u1 = {0, 0, 0, 0};
        if (grow < M) {
          const uint4* ap =
              (const uint4*)((const short*)Avoid + (size_t)grow * D + k0 + akseg);
          u0 = ap[0];
          u1 = ap[1];
        }
        *(uint4*)(As + arow * 72 + akseg) = u0;
        *(uint4*)(As + arow * 72 + akseg + 8) = u1;
      }
    }
    // ---- stage B tile (256 n x 64 k bf16), k-contiguous per n-row ----
    {
      const uint4* wp = (const uint4*)(Wt + (size_t)tid * D + k0);
#pragma unroll
      for (int x = 0; x < 8; x++) *(uint4*)(Bs + tid * 72 + x * 8) = wp[x];
    }
    __syncthreads();
#pragma unroll
    for (int kk = 0; kk < 64; kk += 32) {
      short8 a[4], b[4];
#pragma unroll
      for (int i = 0; i < 4; i++)
        a[i] = *(const short8*)(As + (i * 16 + lm) * 72 + kk + q * 8);
#pragma unroll
      for (int j = 0; j < 4; j++)
        b[j] = *(const short8*)(Bs + (w * 64 + j * 16 + lm) * 72 + kk + q * 8);
#pragma unroll
      for (int i = 0; i < 4; i++)
#pragma unroll
        for (int j = 0; j < 4; j++)
          acc[i][j] = __builtin_amdgcn_mfma_f32_16x16x32_bf16(a[i], b[j],
                                                              acc[i][j], 0, 0, 0);
    }
    __syncthreads();
  }

  // ---- epilogue: D reg r -> row = i*16 + q*4 + r, col = w*64 + j*16 + lm ----
#pragma unroll
  for (int i = 0; i < 4; i++) {
#pragma unroll
    for (int r = 0; r < 4; r++) {
      int row = rowBase + i * 16 + q * 4 + r;
      if (row < M) {
        int rb = 0;
        if (ADD_ROW) rb = batch[row];
        if (!FINAL) {
          short* C = (short*)Cvoid;
#pragma unroll
          for (int j = 0; j < 4; j++) {
            int col = w * 64 + j * 16 + lm;
            float c = acc[i][j][r];
            if (ADD_ROW) c += R[(size_t)rb * D + col];
            C[(size_t)row * D + col] = f2bf(c);
          }
        } else {
          float* C = (float*)Cvoid;
#pragma unroll
          for (int j = 0; j < 4; j++) {
            int col = w * 64 + j * 16 + lm;
            float c = acc[i][j][r];
            if (ADD_ROW) c += R[(size_t)rb * D + col];
            c += bias[col];
            c = LEAKY(c);
            C[(size_t)row * D + col] = c;
          }
        }
      }
    }
  }
}

// ---------------- CSR build --------------------------------------------------
__global__ void count_dst(const int* __restrict__ dst, int* __restrict__ offs,
                          int E) {
  int e = blockIdx.x * 256 + threadIdx.x;
  if (e < E) atomicAdd(&offs[dst[e]], 1);
}

__global__ void scan_blocks(int* __restrict__ offs, int* __restrict__ bsums,
                            int n) {
  __shared__ int tmp[256];
  int i = blockIdx.x * 256 + threadIdx.x;
  int v = (i < n) ? offs[i] : 0;
  tmp[threadIdx.x] = v;
  __syncthreads();
  for (int off = 1; off < 256; off <<= 1) {
    int t = (threadIdx.x >= off) ? tmp[threadIdx.x - off] : 0;
    __syncthreads();
    tmp[threadIdx.x] += t;
    __syncthreads();
  }
  if (i < n) offs[i] = tmp[threadIdx.x] - v;
  if (threadIdx.x == 255) bsums[blockIdx.x] = tmp[255];
}

__global__ void scan_sums(int* __restrict__ bs, int nb) {
  __shared__ int tmp[1024];
  int v = (threadIdx.x < nb) ? bs[threadIdx.x] : 0;
  tmp[threadIdx.x] = v;
  __syncthreads();
  for (int off = 1; off < 1024; off <<= 1) {
    int t = (threadIdx.x >= off) ? tmp[threadIdx.x - off] : 0;
    __syncthreads();
    tmp[threadIdx.x] += t;
    __syncthreads();
  }
  if (threadIdx.x < nb) bs[threadIdx.x] = tmp[threadIdx.x] - v;
}

__global__ void add_offsets(int* __restrict__ offs, const int* __restrict__ bs,
                            int n, int* __restrict__ cursor) {
  int i = blockIdx.x * 256 + threadIdx.x;
  if (i < n) {
    int o = offs[i] + bs[blockIdx.x];
    offs[i] = o;
    cursor[i] = o;
  }
}

__global__ void fill_buckets(const int* __restrict__ src,
                             const int* __restrict__ dst,
                             const float* __restrict__ vals,
                             int* __restrict__ cursor, int* __restrict__ esrc,
                             float* __restrict__ ew, int E) {
  int e = blockIdx.x * 256 + threadIdx.x;
  if (e < E) {
    int p = atomicAdd(&cursor[dst[e]], 1);
    esrc[p] = src[e];
    ew[p] = vals[e];
  }
}

// ---- gather agg (bf16 in/out): out[n] = bf16(leaky(sum w*H[src] + bias)) ---
__global__ __launch_bounds__(256) void aggregate_bf(
    const short* __restrict__ H, const int* __restrict__ offs,
    const int* __restrict__ esrc, const float* __restrict__ ew,
    const float* __restrict__ bias, short* __restrict__ out, int N, int E) {
  int node = blockIdx.x * 4 + (threadIdx.x >> 6);
  if (node >= N) return;
  int lane = threadIdx.x & 63;
  int beg = offs[node];
  int end = (node == N - 1) ? E : offs[node + 1];
  float a0 = 0.f, a1 = 0.f, a2 = 0.f, a3 = 0.f;
  for (int i = beg; i < end; i++) {
    int s = esrc[i];
    float wv = ew[i];
    uint2 pk = ((const uint2*)(H + (size_t)s * D))[lane];
    a0 += wv * bf2f((short)(pk.x & 0xffff));
    a1 += wv * bf2f((short)(pk.x >> 16));
    a2 += wv * bf2f((short)(pk.y & 0xffff));
    a3 += wv * bf2f((short)(pk.y >> 16));
  }
  float4 b = ((const float4*)bias)[lane];
  a0 = LEAKY(a0 + b.x);
  a1 = LEAKY(a1 + b.y);
  a2 = LEAKY(a2 + b.z);
  a3 = LEAKY(a3 + b.w);
  uint2 o;
  o.x = (unsigned)(unsigned short)f2bf(a0) |
        ((unsigned)(unsigned short)f2bf(a1) << 16);
  o.y = (unsigned)(unsigned short)f2bf(a2) |
        ((unsigned)(unsigned short)f2bf(a3) << 16);
  ((uint2*)(out + (size_t)node * D))[lane] = o;
}

// ---- R1[b,:] = leaky(features[root_b]) @ W2[256:512] (fp32) ----------------
__global__ void root_gemm1(const float* __restrict__ X,
                           const int* __restrict__ root_idx,
                           const float* __restrict__ W2,
                           float* __restrict__ R1) {
  __shared__ float a[D];
  int b = blockIdx.x, j = threadIdx.x;
  int r = root_idx[b];
  a[j] = LEAKY(X[(size_t)r * D + j]);
  __syncthreads();
  float acc = 0.f;
#pragma unroll 8
  for (int k = 0; k < D; k++) acc += a[k] * W2[(size_t)(D + k) * D + j];
  R1[b * D + j] = acc;
}

// ---- R2[b,:] = (agg1[root_b]+b1) @ Wl[256:512]  (recompute agg for root) ---
__global__ void root_gemm2(const short* __restrict__ H,
                           const int* __restrict__ root_idx,
                           const int* __restrict__ offs,
                           const int* __restrict__ esrc,
                           const float* __restrict__ ew,
                           const float* __restrict__ b1,
                           const float* __restrict__ Wl, float* __restrict__ R2,
                           int N, int E) {
  __shared__ float a[D];
  int b = blockIdx.x, j = threadIdx.x;
  int r = root_idx[b];
  int beg = offs[r], end = (r == N - 1) ? E : offs[r + 1];
  float acc = b1[j];
  for (int e = beg; e < end; e++)
    acc += ew[e] * bf2f(H[(size_t)esrc[e] * D + j]);
  a[j] = acc;
  __syncthreads();
  float s = 0.f;
#pragma unroll 8
  for (int k = 0; k < D; k++) s += a[k] * Wl[(size_t)(D + k) * D + j];
  R2[b * D + j] = s;
}

extern "C" void kernel_launch(void* const* d_in, const int* in_sizes, int n_in,
                              void* d_out, int out_size, void* d_ws,
                              size_t ws_size, hipStream_t stream) {
  const float* features = (const float*)d_in[0];  // [N,256]
  const float* values   = (const float*)d_in[1];  // [E]
  const float* W1 = (const float*)d_in[2];        // [256,256]
  const float* b1 = (const float*)d_in[3];        // [256]
  const float* W2 = (const float*)d_in[4];        // [512,256]
  const float* b2 = (const float*)d_in[5];        // [256]
  const float* Wl = (const float*)d_in[6];        // [512,256]
  const float* bl = (const float*)d_in[7];        // [256]
  const int* adjs = (const int*)d_in[8];          // [2,E]
  const int* batch = (const int*)d_in[9];         // [N]
  const int* root_idx = (const int*)d_in[10];     // [B]

  const int N = in_sizes[0] / D;
  const int E = in_sizes[1];
  const int B = in_sizes[10];
  const int* srcI = adjs;
  const int* dstI = adjs + E;

  // workspace layout
  short* bf0 = (short*)d_ws;            // h0_bf, then h2_bf   [N*256]
  short* bf1 = bf0 + (size_t)N * D;     // a1_bf, then a2_bf   [N*256]
  short* Wt = bf1 + (size_t)N * D;      // 3 x [256,256] bf16 (n-major)
  float* R1 = (float*)(Wt + (size_t)3 * D * D);  // [B,256]
  float* R2 = R1 + (size_t)B * D;                // [B,256]
  float* ew = R2 + (size_t)B * D;                // [E]
  int* offs = (int*)(ew + E);                    // [N]
  int* cursor = offs + N;                        // [N]
  int* esrc = cursor + N;                        // [E]
  int* bsums = esrc + E;                         // [<=1024]

  const int nb = (N + 255) / 256;  // 391 <= 1024

  // ---- build dst-CSR (reused by both aggregations + root2) ----
  hipMemsetAsync(offs, 0, (size_t)N * sizeof(int), stream);
  count_dst<<<(E + 255) / 256, 256, 0, stream>>>(dstI, offs, E);
  scan_blocks<<<nb, 256, 0, stream>>>(offs, bsums, N);
  scan_sums<<<1, 1024, 0, stream>>>(bsums, nb);
  add_offsets<<<nb, 256, 0, stream>>>(offs, bsums, N, cursor);
  fill_buckets<<<(E + 255) / 256, 256, 0, stream>>>(srcI, dstI, values, cursor,
                                                    esrc, ew, E);

  // ---- weights -> bf16, transposed to [n][k] ----
  transpose_w<<<dim3(8, 8, 3), dim3(32, 32), 0, stream>>>(W1, W2, Wl, Wt);

  const int ggrid = (N + 63) / 64;
  const int aggGrid = (N + 3) / 4;

  // 1) h0 = features @ W1           (fp32 in, bf16 out)
  gemm_mfma<true, false, false><<<ggrid, 256, 0, stream>>>(
      features, Wt, nullptr, nullptr, nullptr, bf0, N);

  // 2) a1 = leaky(segsum(w*h0) + b1)  (bf16)
  aggregate_bf<<<aggGrid, 256, 0, stream>>>(bf0, offs, esrc, ew, b1, bf1, N, E);

  // 3) R1, R2 (root2 recomputes pre-leaky agg1 rows from CSR)
  root_gemm1<<<B, 256, 0, stream>>>(features, root_idx, W2, R1);
  root_gemm2<<<B, 256, 0, stream>>>(bf0, root_idx, offs, esrc, ew, b1, Wl, R2,
                                    N, E);

  // 4) h2 = a1 @ W2_top + R1[batch]   (bf16 in/out; overwrites h0 after root2)
  gemm_mfma<false, true, false><<<ggrid, 256, 0, stream>>>(
      bf1, Wt + (size_t)D * D, R1, batch, nullptr, bf0, N);

  // 5) a2 = leaky(segsum(w*h2) + b2)  (bf16)
  aggregate_bf<<<aggGrid, 256, 0, stream>>>(bf0, offs, esrc, ew, b2, bf1, N, E);

  // 6) out = leaky(a2 @ Wl_top + R2[batch] + bl)  (fp32 out)
  gemm_mfma<false, true, true><<<ggrid, 256, 0, stream>>>(
      bf1, Wt + (size_t)2 * D * D, R2, batch, bl, (float*)d_out, N);
}